// Round 13
// baseline (129.467 us; speedup 1.0000x reference)
//
#include <hip/hip_runtime.h>

// IRNN 8-direction scan. x: [8,32,256,256] f32. Outputs (concat order):
// 0 up, 1 right, 2 down, 3 left, 4 zuoxia, 5 youxia, 6 zuoshang(==zuoxia), 7 youshang.
//
// Round-13: R6 base + ONE change: vertical roles 0,1 (down->out2, up->out0,
// 134 MB) use CACHED stores; diagonal roles (269 MB) stay NT. Model: NT path
// caps ~4.5 TB/s (t_v=90us for 403 NT MB); splitting the write stream across
// the cached path (134+64 MB x = 198 < 256 MB L3, so x stays resident) lets
// both paths run concurrently -> t_v ~71-78. Horizontal untouched (store-path
// insensitive per R12).

namespace {
constexpr int HH = 256;
constexpr int WW = 256;
constexpr int PLANE = HH * WW;                       // 65536
constexpr size_t TEN = (size_t)PLANE * 256;          // elems per output tensor

__device__ __forceinline__ float relu_f(float a) { return fmaxf(a, 0.0f); }

typedef float v4f __attribute__((ext_vector_type(4)));

__device__ __forceinline__ void nt_store4(float* p, const float4& v) {
    v4f t; t.x = v.x; t.y = v.y; t.z = v.z; t.w = v.w;
    __builtin_nontemporal_store(t, (v4f*)p);
}
} // namespace

// ---------- vertical family: one wave (64 threads) per (role, plane) ----------
// role 0: down -> out2 (cached) ; 1: up -> out0 (cached) ;
// role 2: zuoxia -> out4+out6 (NT) ; 3: youxia -> out5 (NT) ; 4: youshang -> out7 (NT)
__global__ __launch_bounds__(64) void irnn_vertical(
    const float* __restrict__ x, float* __restrict__ out,
    const float* __restrict__ wup_p, const float* __restrict__ wdn_p)
{
    const int bid = blockIdx.x;
    const int role = bid >> 8;       // 5 roles x 256 planes
    const int plane = bid & 255;
    const int t = threadIdx.x;       // lane owns columns 4t..4t+3

    const float* xp = x + (size_t)plane * PLANE + t * 4;

    if (role == 0) {                 // top_down: out[h]=relu(out[h-1]*wd+x[h])  [CACHED]
        const float wd = *wdn_p;
        float* op = out + 2 * TEN + (size_t)plane * PLANE + t * 4;
        float4 c = *(const float4*)xp;
        *(float4*)op = c;
        for (int h = 1; h < HH; ++h) {
            float4 v = *(const float4*)(xp + h * WW);
            c.x = relu_f(c.x * wd + v.x);
            c.y = relu_f(c.y * wd + v.y);
            c.z = relu_f(c.z * wd + v.z);
            c.w = relu_f(c.w * wd + v.w);
            *(float4*)(op + h * WW) = c;
        }
    } else if (role == 1) {          // top_up: out[h]=relu(out[h+1]*wu+x[h])  [CACHED]
        const float wu = *wup_p;
        float* op = out + 0 * TEN + (size_t)plane * PLANE + t * 4;
        float4 c = *(const float4*)(xp + (HH - 1) * WW);
        *(float4*)(op + (HH - 1) * WW) = c;
        for (int h = HH - 2; h >= 0; --h) {
            float4 v = *(const float4*)(xp + h * WW);
            c.x = relu_f(c.x * wu + v.x);
            c.y = relu_f(c.y * wu + v.y);
            c.z = relu_f(c.z * wu + v.z);
            c.w = relu_f(c.w * wu + v.w);
            *(float4*)(op + h * WW) = c;
        }
    } else if (role == 2) {          // zuoxia/zuoshang [NT]
        const float wd = *wdn_p;
        float* o4 = out + 4 * TEN + (size_t)plane * PLANE + t * 4;
        float* o6 = out + 6 * TEN + (size_t)plane * PLANE + t * 4;
        float4 c = *(const float4*)xp;   // h=0 row pass-through
        nt_store4(o4, c);
        nt_store4(o6, c);
        for (int h = 1; h < HH; ++h) {
            float4 v = *(const float4*)(xp + h * WW);
            float pw = __shfl_up(c.w, 1);     // lane t-1's element 3 == column 4t-1
            float4 n;
            n.x = (t == 0) ? v.x : relu_f(pw * wd + v.x);   // w==0 pass-through
            n.y = relu_f(c.x * wd + v.y);
            n.z = relu_f(c.y * wd + v.z);
            n.w = relu_f(c.z * wd + v.w);
            nt_store4(o4 + h * WW, n);
            nt_store4(o6 + h * WW, n);
            c = n;
        }
    } else if (role == 3) {          // youxia [NT]
        const float wd = *wdn_p;
        float* o5 = out + 5 * TEN + (size_t)plane * PLANE + t * 4;
        float4 c = *(const float4*)xp;   // h=0 row pass-through
        nt_store4(o5, c);
        for (int h = 1; h < HH; ++h) {
            float4 v = *(const float4*)(xp + h * WW);
            float nx = __shfl_down(c.x, 1);   // lane t+1's element 0 == column 4t+4
            float4 n;
            n.x = relu_f(c.y * wd + v.x);
            n.y = relu_f(c.z * wd + v.y);
            n.z = relu_f(c.w * wd + v.z);
            n.w = (t == 63) ? v.w : relu_f(nx * wd + v.w);  // w==255 pass-through
            nt_store4(o5 + h * WW, n);
            c = n;
        }
    } else {                         // youshang [NT]
        const float wd = *wdn_p;
        float* o7 = out + 7 * TEN + (size_t)plane * PLANE + t * 4;
        float4 c = *(const float4*)(xp + (HH - 1) * WW);   // h=255 pass-through
        nt_store4(o7 + (HH - 1) * WW, c);
        for (int h = HH - 2; h >= 0; --h) {
            float4 v = *(const float4*)(xp + h * WW);
            float pw = __shfl_up(c.w, 1);
            float4 n;
            n.x = (t == 0) ? v.x : relu_f(pw * wd + v.x);   // w==0 pass-through
            n.y = relu_f(c.x * wd + v.y);
            n.z = relu_f(c.y * wd + v.z);
            n.w = relu_f(c.z * wd + v.w);
            nt_store4(o7 + h * WW, n);
            c = n;
        }
    }
}

// ---------- horizontal family: right (out1) and left (out3) ----------
__global__ __launch_bounds__(64) void irnn_horizontal(
    const float* __restrict__ x, float* __restrict__ out,
    const float* __restrict__ wlf_p, const float* __restrict__ wrt_p)
{
    __shared__ float xs[64][33];
    __shared__ float os[64][33];

    const int bid = blockIdx.x;
    const int dir = bid >> 10;        // 0: right, 1: left
    const int rb  = bid & 1023;       // row-block index (1024 blocks of 64 rows)
    const size_t row0 = (size_t)rb * 64;
    const int t = threadIdx.x;
    const int lrow = t >> 3;          // load/store mapping: 8 lanes per row
    const int lcol = (t & 7) * 4;

    const float w = dir ? *wlf_p : *wrt_p;
    float* op = out + (size_t)(dir ? 3 : 1) * TEN;

    float carry = 0.0f;
    for (int ci = 0; ci < 8; ++ci) {
        const int cw = dir ? (7 - ci) : ci;   // chunk order follows scan direction
        const int wbase = cw * 32;

        // load 64 rows x 32 cols (8 passes, 8 rows/pass, 128B/row segments)
        for (int p = 0; p < 8; ++p) {
            const int r = p * 8 + lrow;
            float4 v = *(const float4*)(x + (row0 + r) * WW + wbase + lcol);
            *(float4*)&xs[r][lcol] = v;
        }
        __syncthreads();

        // per-thread scan of own row t within the chunk
        if (dir == 0) {
            for (int j = 0; j < 32; ++j) {
                const float v = xs[t][j];
                const int wg = wbase + j;
                const float o = (wg == 0) ? v : relu_f(carry * w + v);
                carry = o;
                os[t][j] = o;
            }
        } else {
            for (int j = 31; j >= 0; --j) {
                const float v = xs[t][j];
                const int wg = wbase + j;
                const float o = (wg == WW - 1) ? v : relu_f(carry * w + v);
                carry = o;
                os[t][j] = o;
            }
        }
        __syncthreads();

        // coalesced writeout (NT)
        for (int p = 0; p < 8; ++p) {
            const int r = p * 8 + lrow;
            float4 v = *(const float4*)&os[r][lcol];
            nt_store4(op + (row0 + r) * WW + wbase + lcol, v);
        }
        __syncthreads();
    }
}

extern "C" void kernel_launch(void* const* d_in, const int* in_sizes, int n_in,
                              void* d_out, int out_size, void* d_ws, size_t ws_size,
                              hipStream_t stream) {
    const float* x      = (const float*)d_in[0];
    const float* w_up   = (const float*)d_in[1];
    const float* w_down = (const float*)d_in[2];
    const float* w_left = (const float*)d_in[3];
    const float* w_right= (const float*)d_in[4];
    float* out = (float*)d_out;

    hipLaunchKernelGGL(irnn_vertical, dim3(5 * 256), dim3(64), 0, stream,
                       x, out, w_up, w_down);
    hipLaunchKernelGGL(irnn_horizontal, dim3(2 * 1024), dim3(64), 0, stream,
                       x, out, w_left, w_right);
}

// Round 14
// 118.485 us; speedup vs baseline: 1.0927x; 1.0927x over previous
//
#include <hip/hip_runtime.h>

// IRNN 8-direction scan. x: [8,32,256,256] f32. Outputs (concat order):
// 0 up, 1 right, 2 down, 3 left, 4 zuoxia, 5 youxia, 6 zuoshang(==zuoxia), 7 youshang.
//
// Round-14: R6 base (two kernels, all-NT stores) + ONE structural change:
// vertical roles FUSED by scan direction (fwd: down+zuoxia+youxia from one x
// read; bwd: up+youshang). Vertical x reads 320->128 MB, NT writes unchanged.
// Distinguishes model A (NT-path ceiling ~4.4 TB/s -> neutral) from model B
// (aggregate read+write fabric ceiling -> t_v 90 -> ~60-75us).
// Depth-8 prefetch (R8-verified) covers load latency at 2 blocks/CU.

namespace {
constexpr int HH = 256;
constexpr int WW = 256;
constexpr int PLANE = HH * WW;
constexpr size_t TEN = (size_t)PLANE * 256;

__device__ __forceinline__ float relu_f(float a) { return fmaxf(a, 0.0f); }

typedef float v4f __attribute__((ext_vector_type(4)));

__device__ __forceinline__ void nt_store4(float* p, const float4& v) {
    v4f t; t.x = v.x; t.y = v.y; t.z = v.z; t.w = v.w;
    __builtin_nontemporal_store(t, (v4f*)p);
}

__device__ __forceinline__ float4 ld4(const float* p) { return *(const float4*)p; }

// Forward scan rows 1..255 with depth-8 prefetch; step(r, v) consumes row r.
template <typename F>
__device__ __forceinline__ void scan_fwd(const float* xp, F&& step) {
    float4 buf[8];
    #pragma unroll
    for (int k = 0; k < 8; ++k) buf[k] = ld4(xp + (1 + k) * WW);
    #pragma unroll 1
    for (int g = 0; g < 30; ++g) {
        #pragma unroll
        for (int k = 0; k < 8; ++k) {
            const int r = 1 + 8 * g + k;
            float4 v = buf[k];
            buf[k] = ld4(xp + (r + 8) * WW);   // rows 9..248
            step(r, v);
        }
    }
    float4 t7[7];
    #pragma unroll
    for (int k = 0; k < 7; ++k) t7[k] = ld4(xp + (249 + k) * WW);
    #pragma unroll
    for (int k = 0; k < 8; ++k) step(241 + k, buf[k]);
    #pragma unroll
    for (int k = 0; k < 7; ++k) step(249 + k, t7[k]);
}

// Backward scan rows 254..0 with depth-8 prefetch; step(h, v) consumes row h.
template <typename F>
__device__ __forceinline__ void scan_bwd(const float* xp, F&& step) {
    float4 buf[8];
    #pragma unroll
    for (int k = 0; k < 8; ++k) buf[k] = ld4(xp + (254 - k) * WW);
    #pragma unroll 1
    for (int g = 0; g < 30; ++g) {
        #pragma unroll
        for (int k = 0; k < 8; ++k) {
            const int h = 254 - (8 * g + k);
            float4 v = buf[k];
            buf[k] = ld4(xp + (h - 8) * WW);   // rows 246..7
            step(h, v);
        }
    }
    float4 t7[7];
    #pragma unroll
    for (int k = 0; k < 7; ++k) t7[k] = ld4(xp + (6 - k) * WW);
    #pragma unroll
    for (int k = 0; k < 8; ++k) step(14 - k, buf[k]);
    #pragma unroll
    for (int k = 0; k < 7; ++k) step(6 - k, t7[k]);
}
} // namespace

// ---------- vertical family, direction-fused: 512 one-wave blocks ----------
// [0,256):   fwd plane: down->out2, zuoxia->out4+out6, youxia->out5 (one x read)
// [256,512): bwd plane: up->out0, youshang->out7 (one x read)
__global__ __launch_bounds__(64) void irnn_vertical(
    const float* __restrict__ x, float* __restrict__ out,
    const float* __restrict__ wup_p, const float* __restrict__ wdn_p)
{
    const int bid = blockIdx.x;
    const int t = threadIdx.x;

    if (bid < 256) {
        const int plane = bid;
        const float wd = *wdn_p;
        const float* xp = x + (size_t)plane * PLANE + t * 4;
        float* o2 = out + 2 * TEN + (size_t)plane * PLANE + t * 4;
        float* o4 = out + 4 * TEN + (size_t)plane * PLANE + t * 4;
        float* o5 = out + 5 * TEN + (size_t)plane * PLANE + t * 4;
        float* o6 = out + 6 * TEN + (size_t)plane * PLANE + t * 4;

        float4 c2 = ld4(xp);          // h=0 pass-through for all fwd scans
        float4 c4 = c2, c5 = c2;
        nt_store4(o2, c2);
        nt_store4(o4, c4);
        nt_store4(o6, c4);
        nt_store4(o5, c5);

        scan_fwd(xp, [&](int r, float4 v) {
            // down
            c2.x = relu_f(c2.x * wd + v.x);
            c2.y = relu_f(c2.y * wd + v.y);
            c2.z = relu_f(c2.z * wd + v.z);
            c2.w = relu_f(c2.w * wd + v.w);
            nt_store4(o2 + r * WW, c2);
            // zuoxia (out[h][w] = relu(out[h-1][w-1]*wd + x[h][w]))
            {
                float pw = __shfl_up(c4.w, 1);
                float4 n;
                n.x = (t == 0) ? v.x : relu_f(pw * wd + v.x);
                n.y = relu_f(c4.x * wd + v.y);
                n.z = relu_f(c4.y * wd + v.z);
                n.w = relu_f(c4.z * wd + v.w);
                nt_store4(o4 + r * WW, n);
                nt_store4(o6 + r * WW, n);
                c4 = n;
            }
            // youxia (out[h][w] = relu(out[h-1][w+1]*wd + x[h][w]))
            {
                float nx = __shfl_down(c5.x, 1);
                float4 n;
                n.x = relu_f(c5.y * wd + v.x);
                n.y = relu_f(c5.z * wd + v.y);
                n.z = relu_f(c5.w * wd + v.z);
                n.w = (t == 63) ? v.w : relu_f(nx * wd + v.w);
                nt_store4(o5 + r * WW, n);
                c5 = n;
            }
        });
    } else {
        const int plane = bid - 256;
        const float wu = *wup_p;
        const float wd = *wdn_p;
        const float* xp = x + (size_t)plane * PLANE + t * 4;
        float* o0 = out + 0 * TEN + (size_t)plane * PLANE + t * 4;
        float* o7 = out + 7 * TEN + (size_t)plane * PLANE + t * 4;

        float4 c0 = ld4(xp + 255 * WW);   // h=255 pass-through
        float4 c7 = c0;
        nt_store4(o0 + 255 * WW, c0);
        nt_store4(o7 + 255 * WW, c7);

        scan_bwd(xp, [&](int h, float4 v) {
            // up
            c0.x = relu_f(c0.x * wu + v.x);
            c0.y = relu_f(c0.y * wu + v.y);
            c0.z = relu_f(c0.z * wu + v.z);
            c0.w = relu_f(c0.w * wu + v.w);
            nt_store4(o0 + h * WW, c0);
            // youshang (out[h][w] = relu(out[h+1][w-1]*wd + x[h][w]))
            {
                float pw = __shfl_up(c7.w, 1);
                float4 n;
                n.x = (t == 0) ? v.x : relu_f(pw * wd + v.x);
                n.y = relu_f(c7.x * wd + v.y);
                n.z = relu_f(c7.y * wd + v.z);
                n.w = relu_f(c7.z * wd + v.w);
                nt_store4(o7 + h * WW, n);
                c7 = n;
            }
        });
    }
}

// ---------- horizontal family: right (out1) and left (out3), NT stores ----------
__global__ __launch_bounds__(64) void irnn_horizontal(
    const float* __restrict__ x, float* __restrict__ out,
    const float* __restrict__ wlf_p, const float* __restrict__ wrt_p)
{
    __shared__ float xs[64][33];
    __shared__ float os[64][33];

    const int bid = blockIdx.x;
    const int dir = bid >> 10;        // 0: right, 1: left
    const int rb  = bid & 1023;
    const size_t row0 = (size_t)rb * 64;
    const int t = threadIdx.x;
    const int lrow = t >> 3;
    const int lcol = (t & 7) * 4;

    const float w = dir ? *wlf_p : *wrt_p;
    float* op = out + (size_t)(dir ? 3 : 1) * TEN;

    float carry = 0.0f;
    for (int ci = 0; ci < 8; ++ci) {
        const int cw = dir ? (7 - ci) : ci;
        const int wbase = cw * 32;

        for (int p = 0; p < 8; ++p) {
            const int r = p * 8 + lrow;
            float4 v = *(const float4*)(x + (row0 + r) * WW + wbase + lcol);
            *(float4*)&xs[r][lcol] = v;
        }
        __syncthreads();

        if (dir == 0) {
            for (int j = 0; j < 32; ++j) {
                const float v = xs[t][j];
                const int wg = wbase + j;
                const float o = (wg == 0) ? v : relu_f(carry * w + v);
                carry = o;
                os[t][j] = o;
            }
        } else {
            for (int j = 31; j >= 0; --j) {
                const float v = xs[t][j];
                const int wg = wbase + j;
                const float o = (wg == WW - 1) ? v : relu_f(carry * w + v);
                carry = o;
                os[t][j] = o;
            }
        }
        __syncthreads();

        for (int p = 0; p < 8; ++p) {
            const int r = p * 8 + lrow;
            float4 v = *(const float4*)&os[r][lcol];
            nt_store4(op + (row0 + r) * WW + wbase + lcol, v);
        }
        __syncthreads();
    }
}

extern "C" void kernel_launch(void* const* d_in, const int* in_sizes, int n_in,
                              void* d_out, int out_size, void* d_ws, size_t ws_size,
                              hipStream_t stream) {
    const float* x      = (const float*)d_in[0];
    const float* w_up   = (const float*)d_in[1];
    const float* w_down = (const float*)d_in[2];
    const float* w_left = (const float*)d_in[3];
    const float* w_right= (const float*)d_in[4];
    float* out = (float*)d_out;

    hipLaunchKernelGGL(irnn_vertical, dim3(512), dim3(64), 0, stream,
                       x, out, w_up, w_down);
    hipLaunchKernelGGL(irnn_horizontal, dim3(2 * 1024), dim3(64), 0, stream,
                       x, out, w_left, w_right);
}